// Round 2
// baseline (513.346 us; speedup 1.0000x reference)
//
#include <hip/hip_runtime.h>
#include <math.h>

// DILATE / soft-DTW loss on MI355X — round 2: single-wave lockstep DP.
// 512 problems -> 512 blocks x 64 threads (1 wave). No __syncthreads in the
// DP loops: each lane owns 3 consecutive rows, rolling anti-diagonals live in
// registers, cross-lane exchange via __shfl (1 up-shuffle/step forward,
// 2 down-shuffles/step backward). p-series in LDS (read-only after init),
// t-series in per-lane registers. R stored diag-major in d_ws; backward
// reloads with distance-2 prefetch (ping-pong buffers, loop unrolled x2).
// All exp/log in base-2 -> native v_exp_f32 / v_log_f32.

#define NN 160
#define BC_TOT 512
#define B_SZ 64
#define C_SZ 8
#define BIGF 1e10f
#define C2   144.269504089f      // (1/gamma) * log2(e), gamma = 0.01
#define GLN2 0.0069314718056f    // gamma * ln(2):  gamma*ln(s) = GLN2*log2(s)

__device__ __forceinline__ int clampi(int x, int lo, int hi) {
    return x < lo ? lo : (x > hi ? hi : x);
}

__global__ __launch_bounds__(64)
void dtw_fb_kernel(const float* __restrict__ input,
                   const float* __restrict__ target,
                   float* __restrict__ Rg,      // BC_TOT * NN*NN
                   float* __restrict__ sdtw,    // BC_TOT
                   float* __restrict__ wlt)     // BC_TOT
{
    const int k    = blockIdx.x;
    const int lane = threadIdx.x;
    __shared__ float P[NN];

    const float* tg = target + (size_t)k * NN;
    const float* pg = input  + (size_t)k * NN;
    for (int x = lane; x < NN; x += 64) P[x] = pg[x];

    // per-lane t constants: T[3L .. 3L+3] (T[i-1], T[i] for rows i=3L+1..3L+3)
    float tr[4];
    #pragma unroll
    for (int u = 0; u < 4; ++u)
        tr[u] = tg[clampi(3*lane + u, 0, NN-1)];
    __syncthreads();   // one-time: P visible to all lanes (read-only after)

    float* Rk = Rg + (size_t)k * (NN*NN);
    const int r0 = 3*lane + 1;   // row of register slot 0

    // ================= forward =================
    // p1 = diag d-1, p2 = diag d-2 (rows r0..r0+2); b1/b2 = row 3L boundary
    // values of p1/p2 (fetched from lane-1 via shfl; lane 0 = DP border row 0).
    float p1[3], p2[3];
    #pragma unroll
    for (int s = 0; s < 3; ++s) { p1[s] = BIGF; p2[s] = BIGF; }
    float b1 = BIGF;                         // R[0][d-1] = BIG for d>=2
    float b2 = (lane == 0) ? 0.0f : BIGF;    // R[0][0] = 0 at d=2

    int off = 0;  // compact diag-major offset of diag d within Rk
    for (int d = 2; d <= 2*NN; ++d) {
        const int imin = (d - NN > 1) ? (d - NN) : 1;
        const int imax = (d - 1 < NN) ? (d - 1) : NN;
        // q[u] = P[d - 3L - 1 - u]; cell slot s uses P[j-1] = q[s+1]
        float q[4];
        #pragma unroll
        for (int u = 1; u < 4; ++u)
            q[u] = P[clampi(d - 3*lane - 1 - u, 0, NN-1)];
        float cur[3];
        #pragma unroll
        for (int s = 0; s < 3; ++s) {
            const int i = r0 + s;                 // row
            const float a  = (s == 0) ? b2 : p2[s-1];  // R[i-1][j-1]
            const float bu = (s == 0) ? b1 : p1[s-1];  // R[i-1][j]
            const float cl = p1[s];                    // R[i][j-1]
            const float m  = fminf(a, fminf(bu, cl));
            const float ss = exp2f((m - a)*C2) + exp2f((m - bu)*C2)
                           + exp2f((m - cl)*C2);
            const float dt = tr[s] - q[s+1];           // T[i-1] - P[j-1]
            const float r  = dt*dt + m - GLN2 * log2f(ss);
            const bool act = (i <= NN) && (i >= d - NN) && (i <= d - 1);
            cur[s] = act ? r : BIGF;
            if (act) Rk[off + (i - imin)] = r;         // same lane re-reads later
        }
        const float sc = __shfl_up(cur[2], 1);   // row 3L of diag d, from lane-1
        b2 = b1;
        b1 = (lane == 0) ? BIGF : sc;
        #pragma unroll
        for (int s = 0; s < 3; ++s) { p2[s] = p1[s]; p1[s] = cur[s]; }
        off += imax - imin + 1;
    }
    if (lane == 53) sdtw[k] = p1[0];   // R[160][160]

    // ================= backward =================
    // E[i,j] = E_up*w_up + E_lf*w_lf + E_dg*w_dg, w = exp((R_succ - D_succ - R)/g)
    // State: R1/E1 = diag d+1, R2/E2 = diag d+2; *b = row 3L+4 boundary
    // (from lane+1 slot 0 via shfl_down). acc += E * (i-j)^2 on the fly.
    float R1[3], R2[3], E1[3], E2[3];
    #pragma unroll
    for (int s = 0; s < 3; ++s) { R1[s]=0.f; R2[s]=0.f; E1[s]=0.f; E2[s]=0.f; }
    float R1b = 0.f, R2b = 0.f, E1b = 0.f, E2b = 0.f;
    float acc = 0.0f;

    int off_load = NN*NN;
    float bufA[3], bufB[3];
    #pragma unroll
    for (int s = 0; s < 3; ++s) { bufA[s] = 0.f; bufB[s] = 0.f; }

    auto issue = [&](float (&buf)[3], int dd) {
        const int imin = (dd - NN > 1) ? (dd - NN) : 1;
        const int imax = (dd - 1 < NN) ? (dd - 1) : NN;
        const int len  = imax - imin + 1;
        if (len <= 0) return;
        off_load -= len;
        #pragma unroll
        for (int s = 0; s < 3; ++s) {
            const int i = r0 + s;
            if (i >= imin && i <= imax) buf[s] = Rk[off_load + (i - imin)];
        }
    };

    issue(bufA, 2*NN);       // diag 320
    issue(bufB, 2*NN - 1);   // diag 319

    auto step = [&](int d, float (&buf)[3]) {
        float rc[3];
        #pragma unroll
        for (int s = 0; s < 3; ++s) rc[s] = buf[s];
        if (d >= 4) issue(buf, d - 2);       // distance-2 prefetch
        float q[4];
        #pragma unroll
        for (int u = 0; u < 4; ++u)
            q[u] = P[clampi(d - 3*lane - 1 - u, 0, NN-1)];
        float ec[3];
        #pragma unroll
        for (int s = 0; s < 3; ++s) {
            const int i = r0 + s;
            const int j = d - i;
            const float r = rc[s];
            const float R1n = (s < 2) ? R1[s+1] : R1b;  // diag d+1, row i+1
            const float E1n = (s < 2) ? E1[s+1] : E1b;
            const float R2n = (s < 2) ? R2[s+1] : R2b;  // diag d+2, row i+1
            const float E2n = (s < 2) ? E2[s+1] : E2b;
            const float dtu = tr[s+1] - q[s+1];  // T[i]   - P[j-1]  (up)
            const float dtl = tr[s]   - q[s];    // T[i-1] - P[j]    (left)
            const float dtd = tr[s+1] - q[s];    // T[i]   - P[j]    (diag)
            float e_up = (i+1 <= NN)
                       ? E1n   * exp2f((R1n   - dtu*dtu - r)*C2) : 0.0f;
            float e_lf = (j+1 <= NN)
                       ? E1[s] * exp2f((R1[s] - dtl*dtl - r)*C2) : 0.0f;
            float e_dg = (i+1 <= NN && j+1 <= NN)
                       ? E2n   * exp2f((R2n   - dtd*dtd - r)*C2) : 0.0f;
            float e = e_up + e_lf + e_dg;
            e = (i == NN && j == NN) ? 1.0f : e;   // terminal E[N][N] = 1
            const bool act = (i <= NN) && (i >= d - NN) && (i <= d - 1);
            ec[s] = act ? e : 0.0f;
            const float dij = (float)(i - j);
            acc += ec[s] * dij * dij;
        }
        R2b = R1b; E2b = E1b;
        R1b = __shfl_down(rc[0], 1);   // diag d, row 3L+4 (lane+1 slot 0)
        E1b = __shfl_down(ec[0], 1);
        #pragma unroll
        for (int s = 0; s < 3; ++s) {
            R2[s] = R1[s]; R1[s] = rc[s];
            E2[s] = E1[s]; E1[s] = ec[s];
        }
    };

    // unrolled x2 so ping-pong buffer indices stay static (distance-2 prefetch)
    for (int d = 2*NN; d >= 4; d -= 2) { step(d, bufA); step(d - 1, bufB); }
    step(2, bufA);

    // wave-level reduce acc -> wlt[k]
    #pragma unroll
    for (int o = 32; o > 0; o >>= 1) acc += __shfl_down(acc, o);
    if (lane == 0) wlt[k] = acc * (1.0f / (NN * NN));
}

// final reduction: per-batch means + scalar loss. One wave (64 threads = B).
__global__ __launch_bounds__(64)
void finalize_kernel(const float* __restrict__ sdtw,
                     const float* __restrict__ wlt,
                     float* __restrict__ out)
{
    const int b = threadIdx.x;   // 0..63
    float ls = 0.0f, lt = 0.0f;
    #pragma unroll
    for (int c = 0; c < C_SZ; ++c) {
        ls += sdtw[b * C_SZ + c];
        lt += wlt[b * C_SZ + c];
    }
    ls *= (1.0f / C_SZ);
    lt *= (1.0f / C_SZ);
    out[1 + b]        = ls;   // loss_shape
    out[1 + B_SZ + b] = lt;   // loss_temporal
    float v = 0.5f * ls + 0.5f * lt;
    #pragma unroll
    for (int o = 32; o > 0; o >>= 1) v += __shfl_down(v, o);
    if (b == 0) out[0] = v * (1.0f / B_SZ);
}

extern "C" void kernel_launch(void* const* d_in, const int* in_sizes, int n_in,
                              void* d_out, int out_size, void* d_ws, size_t ws_size,
                              hipStream_t stream) {
    const float* input  = (const float*)d_in[0];
    const float* target = (const float*)d_in[1];
    float* out = (float*)d_out;   // 129 floats

    float* Rg   = (float*)d_ws;                      // 512*160*160 floats
    float* sdtw = Rg + (size_t)BC_TOT * NN * NN;
    float* wlt  = sdtw + BC_TOT;

    dtw_fb_kernel<<<BC_TOT, 64, 0, stream>>>(input, target, Rg, sdtw, wlt);
    finalize_kernel<<<1, 64, 0, stream>>>(sdtw, wlt, out);
}

// Round 3
// 388.378 us; speedup vs baseline: 1.3218x; 1.3218x over previous
//
#include <hip/hip_runtime.h>
#include <hip/hip_fp16.h>
#include <math.h>

// DILATE / soft-DTW — round 3: softmax-weight storage.
// Forward DP stores per-cell normalized softmin weights (Wv, Wh) (Wd = 1-Wv-Wh)
// instead of R. Backward E-recursion then needs NO exp/log/R/D:
//   E[i,j] = E[i+1,j]*Wv(i+1,j) + E[i,j+1]*Wh(i,j+1) + E[i+1,j+1]*Wd(i+1,j+1)
// One wave per problem, lanes own 3 rows, rolling diagonals in registers,
// 1 fwd / 3 bwd shuffles per step, weight loads prefetched 4 diagonals ahead.
// fp32 weights (105 MB) if ws allows, else packed fp16 (52 MB).

#define NN 160
#define BC_TOT 512
#define B_SZ 64
#define C_SZ 8
#define BIGF 1e10f
#define C2   144.269504089f      // (1/gamma)*log2(e), gamma = 0.01
#define GLN2 0.0069314718056f    // gamma*ln(2)

__device__ __forceinline__ int clampi(int x, int lo, int hi) {
    return x < lo ? lo : (x > hi ? hi : x);
}
__device__ __forceinline__ float fexp2(float x) {
#if __has_builtin(__builtin_amdgcn_exp2f)
    return __builtin_amdgcn_exp2f(x);      // v_exp_f32
#else
    return exp2f(x);
#endif
}
__device__ __forceinline__ float flog2(float x) {
#if __has_builtin(__builtin_amdgcn_logf)
    return __builtin_amdgcn_logf(x);       // v_log_f32 (log2)
#else
    return log2f(x);
#endif
}
__device__ __forceinline__ float frcp(float x) {
#if __has_builtin(__builtin_amdgcn_rcpf)
    return __builtin_amdgcn_rcpf(x);       // v_rcp_f32
#else
    return 1.0f / x;
#endif
}
__device__ __forceinline__ unsigned pack2(float a, float b) {
    __half2 h = __floats2half2_rn(a, b);
    return __builtin_bit_cast(unsigned, h);
}
__device__ __forceinline__ float2 unpack2(unsigned u) {
    __half2 h = __builtin_bit_cast(__half2, u);
    float2 r; r.x = __low2float(h); r.y = __high2float(h);
    return r;
}

template<bool FP16W>
__global__ __launch_bounds__(64)
void dtw_fb_kernel(const float* __restrict__ input,
                   const float* __restrict__ target,
                   void* __restrict__ Wg,
                   float* __restrict__ sdtw,
                   float* __restrict__ wlt)
{
    const int k    = blockIdx.x;
    const int lane = threadIdx.x;
    __shared__ float P[NN];

    const float* tg = target + (size_t)k * NN;
    const float* pg = input  + (size_t)k * NN;
    for (int x = lane; x < NN; x += 64) P[x] = pg[x];
    float tr[4];
    #pragma unroll
    for (int u = 0; u < 4; ++u) tr[u] = tg[clampi(3*lane + u, 0, NN-1)];
    __syncthreads();   // P visible; read-only afterwards

    float2*   Wf = (float2*)Wg   + (size_t)k * (NN*NN);
    unsigned* Wu = (unsigned*)Wg + (size_t)k * (NN*NN);
    const int r0 = 3*lane + 1;

    // ================= forward: R rolling + weight stores =================
    float p1[3], p2[3];
    #pragma unroll
    for (int s = 0; s < 3; ++s) { p1[s] = BIGF; p2[s] = BIGF; }
    float b1 = BIGF;
    float b2 = (lane == 0) ? 0.0f : BIGF;

    int off = 0;
    for (int d = 2; d <= 2*NN; ++d) {
        const int imin = (d - NN > 1) ? (d - NN) : 1;
        const int imax = (d - 1 < NN) ? (d - 1) : NN;
        float q[4];
        #pragma unroll
        for (int u = 1; u < 4; ++u)
            q[u] = P[clampi(d - 3*lane - 1 - u, 0, NN-1)];
        float cur[3];
        #pragma unroll
        for (int s = 0; s < 3; ++s) {
            const int i = r0 + s;
            const float a  = (s == 0) ? b2 : p2[s-1];  // diag pred R[i-1][j-1]
            const float bu = (s == 0) ? b1 : p1[s-1];  // vert pred R[i-1][j]
            const float cl = p1[s];                    // horiz pred R[i][j-1]
            const float m  = fminf(a, fminf(bu, cl));
            const float ed = fexp2((m - a)  * C2);
            const float ev = fexp2((m - bu) * C2);
            const float eh = fexp2((m - cl) * C2);
            const float ss = ed + ev + eh;
            const float dt = tr[s] - q[s+1];
            const float r  = dt*dt + m - GLN2 * flog2(ss);
            const bool act = (i <= NN) && (i >= d - NN) && (i <= d - 1);
            cur[s] = act ? r : BIGF;
            if (act) {
                const float rs = frcp(ss);
                const int slot = off + (i - imin);
                const float Wv = ev * rs, Wh = eh * rs;
                if constexpr (FP16W) Wu[slot] = pack2(Wv, Wh);
                else { float2 w; w.x = Wv; w.y = Wh; Wf[slot] = w; }
            }
        }
        const float sc = __shfl_up(cur[2], 1);
        b2 = b1;
        b1 = (lane == 0) ? BIGF : sc;
        #pragma unroll
        for (int s = 0; s < 3; ++s) { p2[s] = p1[s]; p1[s] = cur[s]; }
        off += imax - imin + 1;
    }
    if (lane == 53) sdtw[k] = p1[0];   // R[160][160]

    // ================= backward: pure-FMA E recursion =================
    float E1[3]  = {0,0,0}, E2[3]  = {0,0,0};
    float Wv1[3] = {0,0,0}, Wh1[3] = {0,0,0};
    float Wd1[3] = {0,0,0}, Wd2[3] = {0,0,0};
    float E1b = 0.f, E2b = 0.f, Wv1b = 0.f, Wd1b = 0.f, Wd2b = 0.f;
    float acc = 0.0f;
    int off_load = NN * NN;

    // 4-deep prefetch buffers (zero-init: never-written slots must stay
    // finite — they multiply E=0 but must not be NaN)
    float    bv0[3]={0,0,0}, bh0[3]={0,0,0}, bv1[3]={0,0,0}, bh1[3]={0,0,0};
    float    bv2[3]={0,0,0}, bh2[3]={0,0,0}, bv3[3]={0,0,0}, bh3[3]={0,0,0};
    unsigned bp0[3]={0,0,0}, bp1[3]={0,0,0}, bp2[3]={0,0,0}, bp3[3]={0,0,0};

    auto issue = [&](float (&v)[3], float (&h)[3], unsigned (&p)[3], int dd) {
        const int imin = (dd - NN > 1) ? (dd - NN) : 1;
        const int imax = (dd - 1 < NN) ? (dd - 1) : NN;
        if (imax < imin) return;
        off_load -= (imax - imin + 1);
        #pragma unroll
        for (int s = 0; s < 3; ++s) {
            const int i = r0 + s;
            if (i >= imin && i <= imax) {
                const int slot = off_load + (i - imin);
                if constexpr (FP16W) p[s] = Wu[slot];
                else { float2 w = Wf[slot]; v[s] = w.x; h[s] = w.y; }
            }
        }
    };

    auto step = [&](int d, float (&v)[3], float (&h)[3], unsigned (&p)[3]) {
        float Wvc[3], Whc[3], Wdc[3];
        #pragma unroll
        for (int s = 0; s < 3; ++s) {
            if constexpr (FP16W) { float2 w = unpack2(p[s]); Wvc[s] = w.x; Whc[s] = w.y; }
            else                 { Wvc[s] = v[s]; Whc[s] = h[s]; }
            Wdc[s] = 1.0f - Wvc[s] - Whc[s];
        }
        issue(v, h, p, d - 4);               // distance-4 prefetch
        float ec[3];
        #pragma unroll
        for (int s = 0; s < 3; ++s) {
            const int i = r0 + s;
            const int j = d - i;
            const float E1n  = (s < 2) ? E1[s+1]  : E1b;   // E(i+1,j)   d+1
            const float Wv1n = (s < 2) ? Wv1[s+1] : Wv1b;  // Wv(i+1,j)  d+1
            const float E2n  = (s < 2) ? E2[s+1]  : E2b;   // E(i+1,j+1) d+2
            const float Wd2n = (s < 2) ? Wd2[s+1] : Wd2b;  // Wd(i+1,j+1)d+2
            // invalid successors contribute E=0 (gated below), weights finite
            float e = E1n * Wv1n + E1[s] * Wh1[s] + E2n * Wd2n;
            e = (i == NN && j == NN) ? 1.0f : e;           // E[N][N] = 1
            const bool act = (i <= NN) && (i >= d - NN) && (i <= d - 1);
            ec[s] = act ? e : 0.0f;
            const float dij = (float)(2*i - d);            // i - j
            acc += ec[s] * dij * dij;
        }
        // roll state one diagonal down
        E2b  = E1b;  E1b  = __shfl_down(ec[0], 1);
        Wd2b = Wd1b; Wd1b = __shfl_down(Wdc[0], 1);
        Wv1b = __shfl_down(Wvc[0], 1);
        #pragma unroll
        for (int s = 0; s < 3; ++s) {
            E2[s]  = E1[s];  E1[s]  = ec[s];
            Wd2[s] = Wd1[s]; Wd1[s] = Wdc[s];
            Wv1[s] = Wvc[s]; Wh1[s] = Whc[s];
        }
    };

    issue(bv0, bh0, bp0, 2*NN);
    issue(bv1, bh1, bp1, 2*NN - 1);
    issue(bv2, bh2, bp2, 2*NN - 2);
    issue(bv3, bh3, bp3, 2*NN - 3);

    for (int d = 2*NN; d >= 5; d -= 4) {
        step(d,     bv0, bh0, bp0);
        step(d - 1, bv1, bh1, bp1);
        step(d - 2, bv2, bh2, bp2);
        step(d - 3, bv3, bh3, bp3);
    }
    step(4, bv0, bh0, bp0);
    step(3, bv1, bh1, bp1);
    step(2, bv2, bh2, bp2);

    #pragma unroll
    for (int o = 32; o > 0; o >>= 1) acc += __shfl_down(acc, o);
    if (lane == 0) wlt[k] = acc * (1.0f / (NN * NN));
}

__global__ __launch_bounds__(64)
void finalize_kernel(const float* __restrict__ sdtw,
                     const float* __restrict__ wlt,
                     float* __restrict__ out)
{
    const int b = threadIdx.x;   // 0..63
    float ls = 0.0f, lt = 0.0f;
    #pragma unroll
    for (int c = 0; c < C_SZ; ++c) {
        ls += sdtw[b * C_SZ + c];
        lt += wlt[b * C_SZ + c];
    }
    ls *= (1.0f / C_SZ);
    lt *= (1.0f / C_SZ);
    out[1 + b]        = ls;
    out[1 + B_SZ + b] = lt;
    float v = 0.5f * ls + 0.5f * lt;
    #pragma unroll
    for (int o = 32; o > 0; o >>= 1) v += __shfl_down(v, o);
    if (b == 0) out[0] = v * (1.0f / B_SZ);
}

extern "C" void kernel_launch(void* const* d_in, const int* in_sizes, int n_in,
                              void* d_out, int out_size, void* d_ws, size_t ws_size,
                              hipStream_t stream) {
    const float* input  = (const float*)d_in[0];
    const float* target = (const float*)d_in[1];
    float* out = (float*)d_out;   // 129 floats

    const size_t cells  = (size_t)BC_TOT * NN * NN;
    const size_t need32 = cells * sizeof(float2) + 2u * BC_TOT * sizeof(float);

    if (ws_size >= need32) {      // fp32 weights (105 MB)
        float* sdtw = (float*)((char*)d_ws + cells * sizeof(float2));
        float* wlt  = sdtw + BC_TOT;
        dtw_fb_kernel<false><<<BC_TOT, 64, 0, stream>>>(input, target, d_ws, sdtw, wlt);
        finalize_kernel<<<1, 64, 0, stream>>>(sdtw, wlt, out);
    } else {                      // packed fp16 weights (52 MB, proven fit)
        float* sdtw = (float*)((char*)d_ws + cells * sizeof(unsigned));
        float* wlt  = sdtw + BC_TOT;
        dtw_fb_kernel<true><<<BC_TOT, 64, 0, stream>>>(input, target, d_ws, sdtw, wlt);
        finalize_kernel<<<1, 64, 0, stream>>>(sdtw, wlt, out);
    }
}

// Round 4
// 224.547 us; speedup vs baseline: 2.2861x; 1.7296x over previous
//
#include <hip/hip_runtime.h>
#include <math.h>

// DILATE / soft-DTW — round 4: 3-wave phased wavefront pipeline.
// 512 problems -> 512 blocks x 192 threads (3 waves), 1 row per lane
// (thread x owns row x+1; wave0 rows 1-64, wave1 65-128, wave2 129-160).
// Diagonals processed in K=16 chunks; wave w runs chunk c at phase c+w
// (forward) / c+(2-w) (backward), so each wave lags its dependency wave by
// exactly one phase. One __syncthreads per chunk (not per diagonal).
// Cross-wave boundary rows flow through 64-slot LDS rings (written phase t,
// read phase t+1, reused 4 phases later — race-free by construction).
// Forward stores per-cell softmin weights (Wv,Wh) (fp32, diag-major, 105 MB);
// backward is a pure-FMA E recursion on those weights (round-3 identity),
// own-row weights prefetched per chunk into registers.

#define NN     160
#define BC_TOT 512
#define B_SZ   64
#define C_SZ   8
#define BIGF   1e10f
#define C2     144.269504089f     // (1/gamma)*log2(e), gamma = 0.01
#define GLN2   0.0069314718056f   // gamma*ln(2)
#define KPH    16                 // diagonals per phase
#define MBUF   64                 // LDS ring slots (4*KPH)
#define MMSK   63
#define NCHUNK 20                 // ceil(319/16)
#define NPHASE 22                 // NCHUNK + 2 (3-wave pipeline fill)

__device__ __forceinline__ int clampi(int x, int lo, int hi) {
    return x < lo ? lo : (x > hi ? hi : x);
}
__device__ __forceinline__ float fexp2(float x) {
#if __has_builtin(__builtin_amdgcn_exp2f)
    return __builtin_amdgcn_exp2f(x);
#else
    return exp2f(x);
#endif
}
__device__ __forceinline__ float flog2(float x) {
#if __has_builtin(__builtin_amdgcn_logf)
    return __builtin_amdgcn_logf(x);
#else
    return log2f(x);
#endif
}
__device__ __forceinline__ float frcp(float x) {
#if __has_builtin(__builtin_amdgcn_rcpf)
    return __builtin_amdgcn_rcpf(x);
#else
    return 1.0f / x;
#endif
}
// cells in diagonals [2, d)
__device__ __forceinline__ int off_of(int d) {
    if (d <= NN + 2) return ((d - 1) * (d - 2)) >> 1;
    const int m = d - 2 - NN;
    return (NN * (NN + 1)) / 2 + m * NN - ((m * (m + 1)) >> 1);
}
__device__ __forceinline__ int len_of(int d) {
    return (d <= NN + 1) ? (d - 1) : (2 * NN + 1 - d);
}

__global__ __launch_bounds__(192)
void dtw_fb_kernel(const float* __restrict__ input,
                   const float* __restrict__ target,
                   float2* __restrict__ Wg,     // BC_TOT * NN*NN weights
                   float* __restrict__ sdtw,    // BC_TOT
                   float* __restrict__ wlt)     // BC_TOT
{
    const int k    = blockIdx.x;
    const int tid  = threadIdx.x;
    const int w    = tid >> 6;        // wave 0..2
    const int lane = tid & 63;
    const int i    = tid + 1;         // row (valid when tid < NN)
    const bool rowok = (tid < NN);

    __shared__ float P[NN];
    __shared__ float bR[2][MBUF];                       // fwd: rows 64,128
    __shared__ float bE[2][MBUF], bV[2][MBUF], bD[2][MBUF]; // bwd: rows 65,129
    __shared__ float partial[4];

    const float* tg = target + (size_t)k * NN;
    const float* pg = input  + (size_t)k * NN;
    for (int x = tid; x < NN; x += 192) P[x] = pg[x];
    const float tr = rowok ? tg[tid] : 0.0f;
    for (int x = tid; x < 2 * MBUF; x += 192) {
        ((float*)bR)[x] = BIGF;
        ((float*)bE)[x] = 0.0f; ((float*)bV)[x] = 0.0f; ((float*)bD)[x] = 0.0f;
    }
    __syncthreads();

    float2* Wk = Wg + (size_t)k * (NN * NN);

    // ================= forward =================
    // per-lane rolling: r1 = R[i][j-1] (own prev diag), u1 = R[i-1][j] (shfl,
    // prev diag), u2 = R[i-1][j-1] (shfl, prev-prev). Boundary lanes (lane 0
    // of waves 1,2) read rows 64/128 from bR with a 1-step pipelined read.
    float r1 = BIGF, u1 = BIGF, u2 = BIGF;
    float pendR = BIGF, cvd = BIGF;
    const bool fprod = (lane == 63) && (w < 2);
    const bool fcons = (lane == 0) && (w > 0);

    for (int t = 0; t < NPHASE; ++t) {
        const int c = t - w;
        if (c >= 0 && c < NCHUNK) {
            const int dlo = 2 + c * KPH;
            int off = off_of(dlo);
            #pragma unroll 4
            for (int u = 0; u < KPH; ++u) {
                const int d = dlo + u;
                if (d <= 2 * NN) {
                    const int j = d - i;
                    const bool valid = rowok && (j >= 1) && (j <= NN);
                    float vu, vd;
                    if (lane == 0) {
                        if (w == 0) {                 // DP border row 0
                            vu = BIGF;
                            vd = (d == 2) ? 0.0f : BIGF;
                        } else {                      // rows 65,129: LDS
                            const float raw = pendR;  // slot (d-1), issued last step
                            pendR = bR[w - 1][d & MMSK];   // for next step
                            vu = (j >= 1 && j <= NN) ? raw : BIGF;
                            vd = cvd;                 // = guarded vu of prev step
                            cvd = vu;
                        }
                    } else { vu = u1; vd = u2; }
                    const float vl = r1;              // R[i][j-1]; BIG pre-first
                    const float mn = fminf(vd, fminf(vu, vl));
                    const float ed = fexp2((mn - vd) * C2);
                    const float ev = fexp2((mn - vu) * C2);
                    const float eh = fexp2((mn - vl) * C2);
                    const float ss = ed + ev + eh;
                    const int jc = clampi(j - 1, 0, NN - 1);
                    const float dt = tr - P[jc];
                    float r = dt * dt + mn - GLN2 * flog2(ss);
                    if (!valid) r = BIGF;
                    if (valid) {
                        const float rs = frcp(ss);
                        const int imin = (d - NN > 1) ? (d - NN) : 1;
                        float2 ww; ww.x = ev * rs; ww.y = eh * rs;
                        Wk[off + (i - imin)] = ww;    // coalesced across lanes
                    }
                    if (d == 2 * NN && tid == NN - 1) sdtw[k] = r; // R[160][160]
                    if (fprod) bR[w][d & MMSK] = r;   // publish rows 64/128
                    u2 = u1;
                    u1 = __shfl_up(r, 1);
                    r1 = r;
                    off += len_of(d);
                }
            }
        }
        __syncthreads();
    }

    // ================= backward =================
    // E[i,j] = E(i+1,j)*Wv(i+1,j) + E(i,j+1)*Wh(i,j+1) + E(i+1,j+1)*Wd(i+1,j+1)
    // invariant entering step d: nE/nV/nD = neighbor(i+1) @ diag d+1,
    //                            mE/mD    = neighbor(i+1) @ diag d+2,
    //                            e1/wh1   = own (i) @ diag d+1.
    float e1 = 0.0f, wh1 = 0.0f;
    float nE = 0.0f, nV = 0.0f, nD = 0.0f, mE = 0.0f, mD = 0.0f;
    float pE = 0.0f, pV = 0.0f, pD = 0.0f;   // pipelined LDS reads (lane63)
    float acc = 0.0f;
    const bool bcons = (lane == 63) && (w < 2);  // rows 64,128 consume LDS
    const bool bprod = (lane == 0) && (w > 0);   // rows 65,129 publish

    float2 wbuf[KPH];
    #pragma unroll
    for (int u = 0; u < KPH; ++u) { wbuf[u].x = 0.0f; wbuf[u].y = 0.0f; }

    for (int t = 0; t < NPHASE; ++t) {
        const int c = t - (2 - w);               // wave 2 leads
        if (c >= 0 && c < NCHUNK) {
            const int dhi = 2 * NN - c * KPH;
            {   // prefetch own-row weights for this chunk (coalesced/diag)
                int offd = off_of(dhi);
                #pragma unroll
                for (int u = 0; u < KPH; ++u) {
                    const int d = dhi - u;
                    if (d >= 2) {
                        const int imin = (d - NN > 1) ? (d - NN) : 1;
                        const int imax = (d - 1 < NN) ? (d - 1) : NN;
                        if (i >= imin && i <= imax)
                            wbuf[u] = Wk[offd + (i - imin)];
                        offd -= len_of(d - 1);
                    }
                }
            }
            if (bcons && c == 0) {   // prime pend with slot 320 (written 1 phase ago)
                pE = bE[w][(2 * NN) & MMSK];
                pV = bV[w][(2 * NN) & MMSK];
                pD = bD[w][(2 * NN) & MMSK];
            }
            #pragma unroll
            for (int u = 0; u < KPH; ++u) {
                const int d = dhi - u;
                if (d >= 2) {
                    const int j = d - i;
                    const bool valid = rowok && (j >= 1) && (j <= NN);
                    const float Wv = wbuf[u].x, Wh = wbuf[u].y;
                    const float Wd = 1.0f - Wv - Wh;
                    float e = nE * nV + e1 * wh1 + mE * mD;
                    if (i == NN && j == NN) e = 1.0f;    // terminal
                    if (!valid) e = 0.0f;
                    const float dij = (float)(j - i);
                    acc += e * (dij * dij);
                    if (bprod) {                          // publish rows 65/129
                        const int s = d & MMSK;
                        bE[w - 1][s] = e; bV[w - 1][s] = Wv; bD[w - 1][s] = Wd;
                    }
                    const float sE = __shfl_down(e, 1);
                    const float sV = __shfl_down(Wv, 1);
                    const float sD = __shfl_down(Wd, 1);
                    mE = nE; mD = nD;
                    if (bcons) {
                        nE = pE; nV = pV; nD = pD;        // slot d
                        pE = bE[w][(d - 1) & MMSK];       // for next step
                        pV = bV[w][(d - 1) & MMSK];
                        pD = bD[w][(d - 1) & MMSK];
                    } else {
                        nE = sE; nV = sV; nD = sD;
                    }
                    e1 = e; wh1 = Wh;
                }
            }
        }
        __syncthreads();
    }

    // block reduce acc -> wlt[k]
    #pragma unroll
    for (int o = 32; o > 0; o >>= 1) acc += __shfl_down(acc, o);
    if (lane == 0) partial[w] = acc;
    __syncthreads();
    if (tid == 0)
        wlt[k] = (partial[0] + partial[1] + partial[2]) * (1.0f / (NN * NN));
}

// final reduction: per-batch means + scalar loss. One wave (64 threads = B).
__global__ __launch_bounds__(64)
void finalize_kernel(const float* __restrict__ sdtw,
                     const float* __restrict__ wlt,
                     float* __restrict__ out)
{
    const int b = threadIdx.x;   // 0..63
    float ls = 0.0f, lt = 0.0f;
    #pragma unroll
    for (int c = 0; c < C_SZ; ++c) {
        ls += sdtw[b * C_SZ + c];
        lt += wlt[b * C_SZ + c];
    }
    ls *= (1.0f / C_SZ);
    lt *= (1.0f / C_SZ);
    out[1 + b]        = ls;
    out[1 + B_SZ + b] = lt;
    float v = 0.5f * ls + 0.5f * lt;
    #pragma unroll
    for (int o = 32; o > 0; o >>= 1) v += __shfl_down(v, o);
    if (b == 0) out[0] = v * (1.0f / B_SZ);
}

extern "C" void kernel_launch(void* const* d_in, const int* in_sizes, int n_in,
                              void* d_out, int out_size, void* d_ws, size_t ws_size,
                              hipStream_t stream) {
    const float* input  = (const float*)d_in[0];
    const float* target = (const float*)d_in[1];
    float* out = (float*)d_out;   // 129 floats

    const size_t cells = (size_t)BC_TOT * NN * NN;
    float2* Wg   = (float2*)d_ws;                       // 105 MB (fits: proven r3)
    float*  sdtw = (float*)((char*)d_ws + cells * sizeof(float2));
    float*  wlt  = sdtw + BC_TOT;

    dtw_fb_kernel<<<BC_TOT, 192, 0, stream>>>(input, target, Wg, sdtw, wlt);
    finalize_kernel<<<1, 64, 0, stream>>>(sdtw, wlt, out);
}

// Round 6
// 168.447 us; speedup vs baseline: 3.0475x; 1.3330x over previous
//
#include <hip/hip_runtime.h>
#include <math.h>

// DILATE / soft-DTW — round 6: round-5 lean-step pipeline, NaN fix.
// r5 bug: exp2 arg via fma(vd,-C2, mn*C2) — when vd==mn==BIG the fma yields
// the rounding residual of mn*C2 (ulp 2^17 at 1.44e12) => exp2(+65536)=inf
// => ss=inf => r=-inf => NaN cascade. Fix: subtract form (mn - vd)*C2, which
// is exactly 0 when vd==mn and always <= 0 (mn is the min) — no overflow
// possible. Rest identical to r5:
//  - 512 blocks x 192 thr (3 waves), 1 row/lane, K=16-diag chunks,
//    1 barrier/chunk, waves phase-lagged by their dependency distance
//  - forward ungated (BIG propagates exactly), P zero-padded in LDS
//  - validity = one unsigned compare (gates store / e only)
//  - incremental wave-uniform store/load offsets
//  - backward shuffles PRODUCTS e*Wv, e*Wd (2 shuffles, e = 2 FMAs)
//  - terminal E[N][N]=1 pre-seeded; weight prefetch double-buffered
//  - boundary rings broadcast-read + cndmask (no divergent read path)

#define NN     160
#define BC_TOT 512
#define B_SZ   64
#define C_SZ   8
#define BIGF   1e10f
#define C2     144.269504089f     // (1/gamma)*log2(e), gamma = 0.01
#define GLN2   0.0069314718056f   // gamma*ln(2)
#define KPH    16
#define NCHUNK 20                 // 20*16 = 320 diag-steps (incl. 1 pad step)
#define NPHASE 22                 // NCHUNK + 2 pipeline fill

__device__ __forceinline__ float fexp2(float x) {
#if __has_builtin(__builtin_amdgcn_exp2f)
    return __builtin_amdgcn_exp2f(x);
#else
    return exp2f(x);
#endif
}
__device__ __forceinline__ float flog2(float x) {
#if __has_builtin(__builtin_amdgcn_logf)
    return __builtin_amdgcn_logf(x);
#else
    return log2f(x);
#endif
}
__device__ __forceinline__ float frcp(float x) {
#if __has_builtin(__builtin_amdgcn_rcpf)
    return __builtin_amdgcn_rcpf(x);
#else
    return 1.0f / x;
#endif
}

__global__ __launch_bounds__(192)
void dtw_fb_kernel(const float* __restrict__ input,
                   const float* __restrict__ target,
                   float2* __restrict__ Wg,     // BC_TOT * NN*NN weights
                   float* __restrict__ sdtw,
                   float* __restrict__ wlt)
{
    const int k    = blockIdx.x;
    const int tid  = threadIdx.x;
    const int w    = tid >> 6;
    const int lane = tid & 63;
    const bool rowok = (tid < NN);

    __shared__ float Ppad[512];      // P at [192,352), zeros elsewhere
    __shared__ float bRing[3][64];   // fwd boundary R: ring[w] read by wave w (row 64w; ring[0] = BIG const)
    __shared__ float rPv[3][64];     // bwd boundary product e*Wv (ring[w] = row 64(w+1)+1)
    __shared__ float rPd[3][64];     // bwd boundary product e*Wd
    __shared__ float partial[4];

    const float* tg = target + (size_t)k * NN;
    const float* pg = input  + (size_t)k * NN;
    for (int x = tid; x < 512; x += 192) Ppad[x] = 0.0f;
    for (int x = tid; x < 3 * 64; x += 192) {
        ((float*)bRing)[x] = BIGF;
        ((float*)rPv)[x] = 0.0f;
        ((float*)rPd)[x] = 0.0f;
    }
    for (int x = tid; x < NN; x += 192) Ppad[192 + x] = pg[x]; // same thread as zero pass
    const float tr = rowok ? tg[tid] : 0.0f;
    __syncthreads();

    float2* Wk = Wg + (size_t)k * (NN * NN);
    const bool isL0   = (lane == 0);
    const bool isL63p = (lane == 63) && (w < 2);

    // ================= forward =================
    // Ungated: out-of-domain cells carry ~BIG; exp2((mn-BIG)*C2) == 0 exactly,
    // and (mn - x) <= 0 always (mn = min) so exp2 args never overflow.
    float r1 = BIGF, u1 = BIGF, u2 = BIGF;
    float pendR = BIGF;
    float cvd = (tid == 0) ? 0.0f : BIGF;   // R[0][0]=0 enters at d=2 via lane 0
    int   pIdx = 192 - tid;                 // Ppad index of P[j-1] at d=2
    float2* wp = Wk + tid;                  // diag-major cell ptr at d=2

    for (int t = 0; t < NPHASE; ++t) {
        const int c = t - w;
        if (c >= 0 && c < NCHUNK) {
            const int dlo = 2 + c * KPH;
            #pragma unroll
            for (int u = 0; u < KPH; ++u) {
                const int d = dlo + u;               // d=321 pad step: store-masked
                const float pnext = bRing[w][d & 63];    // broadcast read
                const float vu = isL0 ? pendR : u1;      // R[i-1][j]
                const float vd = isL0 ? cvd  : u2;       // R[i-1][j-1]
                cvd = vu; pendR = pnext;
                const float pj = Ppad[pIdx + u];         // P[j-1] (padded)
                const float vl = r1;                     // R[i][j-1]
                const float mn = fminf(vd, fminf(vu, vl));
                // SUBTRACT form is mandatory (see header): exact 0 at the min,
                // always <= 0 — never inf, and weights exact.
                const float ed = fexp2((mn - vd) * C2);
                const float ev = fexp2((mn - vu) * C2);
                const float eh = fexp2((mn - vl) * C2);
                const float ss = ed + ev + eh;
                const float dt = tr - pj;
                const float r  = __builtin_fmaf(dt, dt, mn) - GLN2 * flog2(ss);
                if (bool(((unsigned)(d - 2 - tid) < (unsigned)NN) & rowok)) {
                    const float rs = frcp(ss);
                    float2 ww; ww.x = ev * rs; ww.y = eh * rs;
                    *wp = ww;
                }
                wp += (d <= NN) ? (d - 1) : (2 * NN - d);  // uniform delta
                if (isL63p) bRing[w + 1][d & 63] = r;
                if (d == 2 * NN) { if (tid == NN - 1) sdtw[k] = r; }
                u2 = u1;
                u1 = __shfl_up(r, 1);
                r1 = r;
            }
            pIdx += KPH;
        }
        __syncthreads();
    }

    // ================= backward =================
    // e(i,j) = pv(i+1,j) + e(i,j+1)*Wh(i,j+1) + pd(i+1,j+1)
    // pv = e*Wv, pd = e*Wd travel down-lane via shuffle (rings across waves).
    float acc = 0.0f;
    float e1 = 0.0f, wh1 = 0.0f;
    float t1 = (tid == NN - 1) ? 1.0f : 0.0f;   // seeds E[N][N] = 1 at d=320
    float t3 = 0.0f, hPd = 0.0f;
    int   lOff = (NN * NN - NN + tid) * 8;      // byte offset of idx(d=320)
    const bool isL63c = (lane == 63) && (w < 2);
    const bool isL0p  = (lane == 0) && (w > 0);
    const int  ti2 = 2 * (tid + 1);             // 2*i

    float2 wA[KPH], wB[KPH];
    #pragma unroll
    for (int u = 0; u < KPH; ++u) {
        wA[u].x = 0.f; wA[u].y = 0.f; wB[u].x = 0.f; wB[u].y = 0.f;
    }
    const char* WkC = (const char*)Wk;

    auto load16 = [&](float2 (&buf)[KPH], int dtop) {
        #pragma unroll
        for (int u = 0; u < KPH; ++u) {
            const int d = dtop - u;
            buf[u] = *(const float2*)(WkC + lOff);
            const int dec = (d <= NN + 1) ? (d - 2) : (2 * NN + 1 - d);
            lOff -= dec * 8;
            if (lOff < 0) lOff = 0;             // final-chunk tail clamp
        }
    };

    auto chunk = [&](int dhi, float2 (&buf)[KPH]) {
        #pragma unroll
        for (int u = 0; u < KPH; ++u) {
            const int d = dhi - u;
            const float rv = rPv[w][(d + 1) & 63];   // broadcast reads
            const float rd = rPd[w][(d + 2) & 63];
            const float T1 = isL63c ? rv : t1;
            const float T3 = isL63c ? rd : t3;
            float e = __builtin_fmaf(e1, wh1, T1) + T3;
            const bool ok = bool(((unsigned)(d - 2 - tid) < (unsigned)NN) & rowok);
            e = ok ? e : 0.0f;
            const float dij = (float)(d - ti2);      // j - i
            acc = __builtin_fmaf(e * dij, dij, acc);
            const float Wv = buf[u].x, Wh = buf[u].y;
            const float pv = e * Wv;
            const float pd = e * (1.0f - Wv - Wh);
            if (isL0p) { rPv[w - 1][d & 63] = pv; rPd[w - 1][d & 63] = pd; }
            const float sv = __shfl_down(pv, 1);
            const float sd = __shfl_down(pd, 1);
            t1 = sv;          // pv @ diag d -> term1 at step d-1
            t3 = hPd;         // pd @ diag d+1 -> term3 at step d-1
            hPd = sd;
            e1 = e; wh1 = Wh;
        }
    };

    for (int t = 0; t < NPHASE; ++t) {
        const int c = t - (2 - w);               // wave 2 leads
        if (c >= 0 && c < NCHUNK) {
            const int dhi = 2 * NN - c * KPH;
            if ((c & 1) == 0) {
                if (c == 0) load16(wA, dhi);                 // prime (exposed once)
                if (c + 1 < NCHUNK) load16(wB, dhi - KPH);   // prefetch next phase
                chunk(dhi, wA);
            } else {
                if (c + 1 < NCHUNK) load16(wA, dhi - KPH);
                chunk(dhi, wB);
            }
        }
        __syncthreads();
    }

    // block reduce acc -> wlt[k]
    #pragma unroll
    for (int o = 32; o > 0; o >>= 1) acc += __shfl_down(acc, o);
    if (lane == 0) partial[w] = acc;
    __syncthreads();
    if (tid == 0)
        wlt[k] = (partial[0] + partial[1] + partial[2]) * (1.0f / (NN * NN));
}

// final reduction: per-batch means + scalar loss. One wave (64 threads = B).
__global__ __launch_bounds__(64)
void finalize_kernel(const float* __restrict__ sdtw,
                     const float* __restrict__ wlt,
                     float* __restrict__ out)
{
    const int b = threadIdx.x;   // 0..63
    float ls = 0.0f, lt = 0.0f;
    #pragma unroll
    for (int c = 0; c < C_SZ; ++c) {
        ls += sdtw[b * C_SZ + c];
        lt += wlt[b * C_SZ + c];
    }
    ls *= (1.0f / C_SZ);
    lt *= (1.0f / C_SZ);
    out[1 + b]        = ls;
    out[1 + B_SZ + b] = lt;
    float v = 0.5f * ls + 0.5f * lt;
    #pragma unroll
    for (int o = 32; o > 0; o >>= 1) v += __shfl_down(v, o);
    if (b == 0) out[0] = v * (1.0f / B_SZ);
}

extern "C" void kernel_launch(void* const* d_in, const int* in_sizes, int n_in,
                              void* d_out, int out_size, void* d_ws, size_t ws_size,
                              hipStream_t stream) {
    const float* input  = (const float*)d_in[0];
    const float* target = (const float*)d_in[1];
    float* out = (float*)d_out;   // 129 floats

    const size_t cells = (size_t)BC_TOT * NN * NN;
    float2* Wg   = (float2*)d_ws;                       // 105 MB (fits, proven r3/r4)
    float*  sdtw = (float*)((char*)d_ws + cells * sizeof(float2));
    float*  wlt  = sdtw + BC_TOT;

    dtw_fb_kernel<<<BC_TOT, 192, 0, stream>>>(input, target, Wg, sdtw, wlt);
    finalize_kernel<<<1, 64, 0, stream>>>(sdtw, wlt, out);
}

// Round 7
// 165.858 us; speedup vs baseline: 3.0951x; 1.0156x over previous
//
#include <hip/hip_runtime.h>
#include <math.h>

// DILATE / soft-DTW — round 7: LDS-only barriers + batched ring reads.
// r6 analysis: 183 cyc wall/step vs ~50 busy. Two stall sources removed:
//  1) __syncthreads drains vmcnt(0) (m97 behavior) at all 44 phase barriers,
//     waiting on global weight stores/prefetches. Unnecessary: each lane
//     reads back only cells IT wrote (lane tid owns row tid+1 in fwd AND
//     bwd) — no cross-thread global deps. Cross-wave data moves ONLY via
//     LDS rings => barrier needs lgkmcnt(0) only. Custom barrier:
//     s_waitcnt(lgkm only) + s_barrier.
//  2) per-step LDS ring reads sat on the serial chain (~120 cyc latency).
//     Now ALL ring slots a chunk needs (17) are batch-loaded into registers
//     right after the barrier (statically unrolled indices) — zero DS reads
//     in the steady-state chain. Slot liveness verified: consumer slots
//     [dlo-2,dlo+14] fwd / [dhi-14,dhi+2] bwd are written 1-2 phases ago,
//     disjoint from producer's concurrent-phase writes (64-slot ring,
//     16/phase => 4-phase reuse distance).
// Rest identical to r6 (3-wave phased pipeline, softmin-weight backward,
// subtract-form exp2 args — mandatory, see r5 NaN post-mortem).

#define NN     160
#define BC_TOT 512
#define B_SZ   64
#define C_SZ   8
#define BIGF   1e10f
#define C2     144.269504089f     // (1/gamma)*log2(e), gamma = 0.01
#define GLN2   0.0069314718056f   // gamma*ln(2)
#define KPH    16
#define NCHUNK 20                 // 20*16 = 320 diag-steps (incl. 1 pad step)
#define NPHASE 22                 // NCHUNK + 2 pipeline fill

__device__ __forceinline__ float fexp2(float x) {
#if __has_builtin(__builtin_amdgcn_exp2f)
    return __builtin_amdgcn_exp2f(x);
#else
    return exp2f(x);
#endif
}
__device__ __forceinline__ float flog2(float x) {
#if __has_builtin(__builtin_amdgcn_logf)
    return __builtin_amdgcn_logf(x);
#else
    return log2f(x);
#endif
}
__device__ __forceinline__ float frcp(float x) {
#if __has_builtin(__builtin_amdgcn_rcpf)
    return __builtin_amdgcn_rcpf(x);
#else
    return 1.0f / x;
#endif
}

// Workgroup barrier that orders LDS only (lgkmcnt(0)), skipping the vmcnt(0)
// drain __syncthreads would emit. Safe here: no cross-thread global-memory
// dependencies anywhere in this kernel (see header). simm16 0xC07F =
// vmcnt(63) expcnt(7) lgkmcnt(0) on gfx9-family encoding.
__device__ __forceinline__ void barrier_lds() {
#if __has_builtin(__builtin_amdgcn_s_waitcnt) && __has_builtin(__builtin_amdgcn_s_barrier)
    __asm__ __volatile__("" ::: "memory");
    __builtin_amdgcn_s_waitcnt(0xC07F);
    __builtin_amdgcn_s_barrier();
    __asm__ __volatile__("" ::: "memory");
#else
    __syncthreads();
#endif
}

__global__ __launch_bounds__(192)
void dtw_fb_kernel(const float* __restrict__ input,
                   const float* __restrict__ target,
                   float2* __restrict__ Wg,     // BC_TOT * NN*NN weights
                   float* __restrict__ sdtw,
                   float* __restrict__ wlt)
{
    const int k    = blockIdx.x;
    const int tid  = threadIdx.x;
    const int w    = tid >> 6;
    const int lane = tid & 63;
    const bool rowok = (tid < NN);

    __shared__ float Ppad[512];      // P at [192,352), zeros elsewhere
    __shared__ float bRing[3][64];   // fwd boundary R; ring[w] read by wave w
    __shared__ float rPv[3][64];     // bwd boundary product e*Wv; ring[w] read by wave w
    __shared__ float rPd[3][64];     // bwd boundary product e*Wd
    __shared__ float partial[4];

    const float* tg = target + (size_t)k * NN;
    const float* pg = input  + (size_t)k * NN;
    for (int x = tid; x < 512; x += 192) Ppad[x] = 0.0f;
    for (int x = tid; x < 3 * 64; x += 192) {
        ((float*)bRing)[x] = BIGF;
        ((float*)rPv)[x] = 0.0f;
        ((float*)rPd)[x] = 0.0f;
    }
    for (int x = tid; x < NN; x += 192) Ppad[192 + x] = pg[x]; // same thread as zero pass
    const float tr = rowok ? tg[tid] : 0.0f;
    barrier_lds();

    float2* Wk = Wg + (size_t)k * (NN * NN);
    const bool isL0    = (lane == 0);
    const bool isL63p  = (lane == 63) && (w < 2);
    const bool useRing = (w > 0);
    const float seed0  = (tid == 0) ? 0.0f : BIGF;   // R[0][0]=0 enters at d=2

    // ================= forward =================
    // Ungated: out-of-domain cells carry ~BIG; (mn - x) <= 0 always (mn = min)
    // so exp2 args never overflow, exp2((mn-BIG)*C2) == 0 exactly.
    float r1 = BIGF, u1 = BIGF, u2 = BIGF;
    int   pIdx = 192 - tid;                 // Ppad index of P[j-1] at d=2
    float2* wp = Wk + tid;                  // diag-major cell ptr at d=2

    for (int t = 0; t < NPHASE; ++t) {
        const int c = t - w;
        if (c >= 0 && c < NCHUNK) {
            const int dlo = 2 + c * KPH;
            // batch ring slots [dlo-2, dlo+14] -> registers (static indices)
            float rg[KPH + 1];
            #pragma unroll
            for (int x = 0; x <= KPH; ++x)
                rg[x] = bRing[w][(dlo - 2 + x) & 63];
            #pragma unroll
            for (int u = 0; u < KPH; ++u) {
                const int d = dlo + u;               // d=321 pad step: store-masked
                const float subU = useRing ? rg[u + 1] : BIGF;  // R[i-1][j]   @ d-1
                float       subD = useRing ? rg[u]     : BIGF;  // R[i-1][j-1] @ d-2
                if (u == 0) subD = (c == 0) ? seed0 : subD;     // d==2 seed
                const float vu = isL0 ? subU : u1;
                const float vd = isL0 ? subD : u2;
                const float pj = Ppad[pIdx + u];         // P[j-1] (padded)
                const float vl = r1;                     // R[i][j-1]
                const float mn = fminf(vd, fminf(vu, vl));
                // SUBTRACT form mandatory (r5 post-mortem): exact 0 at the
                // min, always <= 0 — never inf, weights exact.
                const float ed = fexp2((mn - vd) * C2);
                const float ev = fexp2((mn - vu) * C2);
                const float eh = fexp2((mn - vl) * C2);
                const float ss = ed + ev + eh;
                const float dt = tr - pj;
                const float r  = __builtin_fmaf(dt, dt, mn) - GLN2 * flog2(ss);
                if (bool(((unsigned)(d - 2 - tid) < (unsigned)NN) & rowok)) {
                    const float rs = frcp(ss);
                    float2 ww; ww.x = ev * rs; ww.y = eh * rs;
                    *wp = ww;
                }
                wp += (d <= NN) ? (d - 1) : (2 * NN - d);  // uniform delta
                if (isL63p) bRing[w + 1][d & 63] = r;
                if (d == 2 * NN) { if (tid == NN - 1) sdtw[k] = r; }
                u2 = u1;
                u1 = __shfl_up(r, 1);
                r1 = r;
            }
            pIdx += KPH;
        }
        barrier_lds();
    }

    // ================= backward =================
    // e(i,j) = pv(i+1,j) + e(i,j+1)*Wh(i,j+1) + pd(i+1,j+1)
    // pv = e*Wv, pd = e*Wd travel down-lane via shuffle (rings across waves).
    float acc = 0.0f;
    float e1 = 0.0f, wh1 = 0.0f;
    float t1 = (tid == NN - 1) ? 1.0f : 0.0f;   // seeds E[N][N] = 1 at d=320
    float t3 = 0.0f, hPd = 0.0f;
    int   lOff = (NN * NN - NN + tid) * 8;      // byte offset of idx(d=320)
    const bool isL63c = (lane == 63) && (w < 2);
    const bool isL0p  = (lane == 0) && (w > 0);
    const int  ti2 = 2 * (tid + 1);             // 2*i

    float2 wA[KPH], wB[KPH];
    #pragma unroll
    for (int u = 0; u < KPH; ++u) {
        wA[u].x = 0.f; wA[u].y = 0.f; wB[u].x = 0.f; wB[u].y = 0.f;
    }
    const char* WkC = (const char*)Wk;

    auto load16 = [&](float2 (&buf)[KPH], int dtop) {
        #pragma unroll
        for (int u = 0; u < KPH; ++u) {
            const int d = dtop - u;
            buf[u] = *(const float2*)(WkC + lOff);
            const int dec = (d <= NN + 1) ? (d - 2) : (2 * NN + 1 - d);
            lOff -= dec * 8;
            if (lOff < 0) lOff = 0;             // final-chunk tail clamp
        }
    };

    auto chunk = [&](int dhi, float2 (&buf)[KPH]) {
        // batch ring slots [dhi-14, dhi+2] -> registers (static indices)
        float sv[KPH + 1], sq[KPH + 1];
        #pragma unroll
        for (int x = 0; x <= KPH; ++x) {
            const int slot = (dhi + 2 - x) & 63;
            sv[x] = rPv[w][slot];
            sq[x] = rPd[w][slot];
        }
        #pragma unroll
        for (int u = 0; u < KPH; ++u) {
            const int d = dhi - u;
            const float T1 = isL63c ? sv[u + 1] : t1;   // pv @ (i+1, diag d+1)
            const float T3 = isL63c ? sq[u]     : t3;   // pd @ (i+1, diag d+2)
            float e = __builtin_fmaf(e1, wh1, T1) + T3;
            const bool ok = bool(((unsigned)(d - 2 - tid) < (unsigned)NN) & rowok);
            e = ok ? e : 0.0f;
            const float dij = (float)(d - ti2);      // j - i
            acc = __builtin_fmaf(e * dij, dij, acc);
            const float Wv = buf[u].x, Wh = buf[u].y;
            const float pv = e * Wv;
            const float pd = e * (1.0f - Wv - Wh);
            if (isL0p) { rPv[w - 1][d & 63] = pv; rPd[w - 1][d & 63] = pd; }
            const float svn = __shfl_down(pv, 1);
            const float sdn = __shfl_down(pd, 1);
            t1 = svn;         // pv @ diag d -> term1 at step d-1
            t3 = hPd;         // pd @ diag d+1 -> term3 at step d-1
            hPd = sdn;
            e1 = e; wh1 = Wh;
        }
    };

    for (int t = 0; t < NPHASE; ++t) {
        const int c = t - (2 - w);               // wave 2 leads
        if (c >= 0 && c < NCHUNK) {
            const int dhi = 2 * NN - c * KPH;
            if ((c & 1) == 0) {
                if (c == 0) load16(wA, dhi);                 // prime (exposed once)
                if (c + 1 < NCHUNK) load16(wB, dhi - KPH);   // prefetch next phase
                chunk(dhi, wA);
            } else {
                if (c + 1 < NCHUNK) load16(wA, dhi - KPH);
                chunk(dhi, wB);
            }
        }
        barrier_lds();
    }

    // block reduce acc -> wlt[k]
    #pragma unroll
    for (int o = 32; o > 0; o >>= 1) acc += __shfl_down(acc, o);
    if (lane == 0) partial[w] = acc;
    barrier_lds();
    if (tid == 0)
        wlt[k] = (partial[0] + partial[1] + partial[2]) * (1.0f / (NN * NN));
}

// final reduction: per-batch means + scalar loss. One wave (64 threads = B).
__global__ __launch_bounds__(64)
void finalize_kernel(const float* __restrict__ sdtw,
                     const float* __restrict__ wlt,
                     float* __restrict__ out)
{
    const int b = threadIdx.x;   // 0..63
    float ls = 0.0f, lt = 0.0f;
    #pragma unroll
    for (int c = 0; c < C_SZ; ++c) {
        ls += sdtw[b * C_SZ + c];
        lt += wlt[b * C_SZ + c];
    }
    ls *= (1.0f / C_SZ);
    lt *= (1.0f / C_SZ);
    out[1 + b]        = ls;
    out[1 + B_SZ + b] = lt;
    float v = 0.5f * ls + 0.5f * lt;
    #pragma unroll
    for (int o = 32; o > 0; o >>= 1) v += __shfl_down(v, o);
    if (b == 0) out[0] = v * (1.0f / B_SZ);
}

extern "C" void kernel_launch(void* const* d_in, const int* in_sizes, int n_in,
                              void* d_out, int out_size, void* d_ws, size_t ws_size,
                              hipStream_t stream) {
    const float* input  = (const float*)d_in[0];
    const float* target = (const float*)d_in[1];
    float* out = (float*)d_out;   // 129 floats

    const size_t cells = (size_t)BC_TOT * NN * NN;
    float2* Wg   = (float2*)d_ws;                       // 105 MB (fits, proven r3-r6)
    float*  sdtw = (float*)((char*)d_ws + cells * sizeof(float2));
    float*  wlt  = sdtw + BC_TOT;

    dtw_fb_kernel<<<BC_TOT, 192, 0, stream>>>(input, target, Wg, sdtw, wlt);
    finalize_kernel<<<1, 64, 0, stream>>>(sdtw, wlt, out);
}

// Round 8
// 148.951 us; speedup vs baseline: 3.4464x; 1.1135x over previous
//
#include <hip/hip_runtime.h>
#include <math.h>

// DILATE / soft-DTW — round 8: chunk skipping + DPP lane shifts + linear rings.
// r7 post-mortem: 381 cyc wall/slot, 58 instr/wave-step, 45% VALUBusy.
// Changes:
//  1) CHUNK SKIP: wave w's rows are valid only in diags [64w+2, 64w+224]
//     (14 of 20 chunks fwd, sym. bwd). Fully-masked chunks are now skipped
//     (wave-uniform range check) — ~30% of issued instructions eliminated;
//     the co-resident block's waves absorb the freed issue slots.
//  2) DPP SHIFTS: in-chain __shfl (DS pipe, ~40 cyc) replaced by gfx9
//     full-wave DPP shifts (wave_shr1=0x138 for shfl_up, wave_shl1=0x130
//     for shfl_down; rocPRIM scan idiom) — 1 VALU op, ~4-8 cyc. Edge lanes
//     (0/63) get bound_ctrl=0 garbage but are overridden by ring cndmasks.
//  3) LINEAR RINGS: boundary arrays are full 328-slot linear arrays (no &63);
//     unwritten slots = init value (BIG fwd / 0 bwd) which is exactly the
//     correct out-of-range semantics under chunk skipping; 17-slot batch
//     reads become contiguous (b128-mergeable).
// Kept from r6/r7: 3-wave phased pipeline (1 barrier/chunk, lgkm-only
// barrier), softmin-weight backward (pure FMA), subtract-form exp2 args
// (mandatory — r5 NaN post-mortem), double-buffered weight prefetch.

#define NN     160
#define BC_TOT 512
#define B_SZ   64
#define C_SZ   8
#define BIGF   1e10f
#define C2     144.269504089f     // (1/gamma)*log2(e), gamma = 0.01
#define GLN2   0.0069314718056f   // gamma*ln(2)
#define KPH    16
#define NCHUNK 20                 // 320 diag-steps (incl. 1 pad)
#define NPHASE 22                 // NCHUNK + 2 pipeline fill
#define RSZ    328                // linear ring size (slots 0..322 used)

__device__ __forceinline__ float fexp2(float x) {
#if __has_builtin(__builtin_amdgcn_exp2f)
    return __builtin_amdgcn_exp2f(x);
#else
    return exp2f(x);
#endif
}
__device__ __forceinline__ float flog2(float x) {
#if __has_builtin(__builtin_amdgcn_logf)
    return __builtin_amdgcn_logf(x);
#else
    return log2f(x);
#endif
}
__device__ __forceinline__ float frcp(float x) {
#if __has_builtin(__builtin_amdgcn_rcpf)
    return __builtin_amdgcn_rcpf(x);
#else
    return 1.0f / x;
#endif
}
// lane i <- lane i-1 (lane 0: own value — always overridden by consumer)
__device__ __forceinline__ float dpp_up1(float x) {
    int xi = __builtin_bit_cast(int, x);
    return __builtin_bit_cast(float,
        __builtin_amdgcn_update_dpp(xi, xi, 0x138, 0xF, 0xF, false)); // wave_shr1
}
// lane i <- lane i+1 (lane 63: own value — always overridden by consumer)
__device__ __forceinline__ float dpp_dn1(float x) {
    int xi = __builtin_bit_cast(int, x);
    return __builtin_bit_cast(float,
        __builtin_amdgcn_update_dpp(xi, xi, 0x130, 0xF, 0xF, false)); // wave_shl1
}
// LDS-only barrier (skip vmcnt drain — no cross-thread global deps here).
// simm16 0xC07F = vmcnt(63) expcnt(7) lgkmcnt(0).
__device__ __forceinline__ void barrier_lds() {
    __asm__ __volatile__("" ::: "memory");
    __builtin_amdgcn_s_waitcnt(0xC07F);
    __builtin_amdgcn_s_barrier();
    __asm__ __volatile__("" ::: "memory");
}
// cells in diagonals [2, d)
__device__ __forceinline__ int off_of(int d) {
    if (d <= NN + 2) return ((d - 1) * (d - 2)) >> 1;
    const int m = d - 2 - NN;
    return (NN * (NN + 1)) / 2 + m * NN - ((m * (m + 1)) >> 1);
}

__global__ __launch_bounds__(192)
void dtw_fb_kernel(const float* __restrict__ input,
                   const float* __restrict__ target,
                   float2* __restrict__ Wg,     // BC_TOT * NN*NN weights
                   float* __restrict__ sdtw,
                   float* __restrict__ wlt)
{
    const int k    = blockIdx.x;
    const int tid  = threadIdx.x;
    const int w    = tid >> 6;
    const int lane = tid & 63;
    const bool rowok = (tid < NN);

    __shared__ float Ppad[512];      // P at [192,352), zeros elsewhere
    __shared__ float bR[2][RSZ];     // fwd boundary R: written by wave w, read by wave w+1 as bR[w]
    __shared__ float rV[2][RSZ];     // bwd product e*Wv: written by wave w+1, read by wave w as rV[w]
    __shared__ float rD[2][RSZ];     // bwd product e*Wd
    __shared__ float partial[4];

    const float* tg = target + (size_t)k * NN;
    const float* pg = input  + (size_t)k * NN;
    for (int x = tid; x < 512; x += 192) Ppad[x] = 0.0f;
    for (int x = tid; x < 2 * RSZ; x += 192) {
        ((float*)bR)[x] = BIGF;     // unwritten slot == border BIG (correct)
        ((float*)rV)[x] = 0.0f;     // unwritten slot == E 0 (correct)
        ((float*)rD)[x] = 0.0f;
    }
    for (int x = tid; x < NN; x += 192) Ppad[192 + x] = pg[x]; // same thread as zero pass
    const float tr = rowok ? tg[tid] : 0.0f;
    barrier_lds();

    float2* Wk = Wg + (size_t)k * (NN * NN);
    const bool isL0    = (lane == 0);
    const bool isL63p  = (lane == 63) && (w < 2);
    const bool useRing = (w > 0);

    // ================= forward =================
    // Wave w active chunks: [4w, min(19, 4w+13)] (its rows valid in
    // d ∈ [64w+2, 64w+224]). Outside: skip (state BIG-correct by init).
    const int cLoF = 4 * w;
    const int cHiF = (4 * w + 13 < NCHUNK - 1) ? 4 * w + 13 : NCHUNK - 1;
    float r1 = BIGF, u1 = BIGF, u2 = BIGF;
    int   pIdx = 192 + KPH * cLoF - tid;          // Ppad idx of P[j-1] at first chunk
    float2* wp = Wk + tid + off_of(2 + KPH * cLoF);

    for (int t = 0; t < NPHASE; ++t) {
        const int c = t - w;
        if (c >= cLoF && c <= cHiF) {
            const int dlo = 2 + c * KPH;
            float rg[KPH + 1];
            if (useRing) {
                #pragma unroll
                for (int x = 0; x <= KPH; ++x) rg[x] = bR[w - 1][dlo - 2 + x];
            }
            #pragma unroll
            for (int u = 0; u < KPH; ++u) {
                const int d = dlo + u;
                const float subU = useRing ? rg[u + 1]
                                           : BIGF;                    // R[i-1][j]
                const float subD = useRing ? rg[u]
                                           : ((c == 0 && u == 0) ? 0.0f : BIGF); // R[i-1][j-1]; R[0][0]=0 seed
                const float vu = isL0 ? subU : u1;
                const float vd = isL0 ? subD : u2;
                const float pj = Ppad[pIdx + u];         // P[j-1] (zero-padded)
                const float vl = r1;                     // R[i][j-1]
                const float mn = fminf(vd, fminf(vu, vl));
                // SUBTRACT form mandatory (r5 post-mortem): exact 0 at the
                // min, always <= 0 — never inf, weights exact.
                const float ed = fexp2((mn - vd) * C2);
                const float ev = fexp2((mn - vu) * C2);
                const float eh = fexp2((mn - vl) * C2);
                const float ss = ed + ev + eh;
                const float dt = tr - pj;
                const float r  = __builtin_fmaf(flog2(ss), -GLN2,
                                 __builtin_fmaf(dt, dt, mn));
                if (bool(((unsigned)(d - 2 - tid) < (unsigned)NN) & rowok)) {
                    const float rs = frcp(ss);
                    float2 ww; ww.x = ev * rs; ww.y = eh * rs;
                    *wp = ww;
                }
                wp += (d <= NN) ? (d - 1) : (2 * NN - d);  // wave-uniform delta
                if (isL63p) bR[w][d] = r;
                if (d == 2 * NN) { if (tid == NN - 1) sdtw[k] = r; }
                u2 = u1;
                u1 = dpp_up1(r);
                r1 = r;
            }
            pIdx += KPH;
        }
        barrier_lds();
    }

    // ================= backward =================
    // e(i,j) = pv(i+1,j) + e(i,j+1)*Wh(i,j+1) + pd(i+1,j+1); pv=e*Wv, pd=e*Wd.
    // Wave w active chunks: [max(0,6-4w), 19-4w].
    float acc = 0.0f;
    float e1 = 0.0f, wh1 = 0.0f;
    float t1 = (tid == NN - 1) ? 1.0f : 0.0f;   // seeds E[N][N]=1 at d=320
    float t3 = 0.0f, hPd = 0.0f;
    const int cLoB = (6 - 4 * w > 0) ? 6 - 4 * w : 0;
    const int cHiB = NCHUNK - 1 - 4 * w;
    const int dTop = 2 * NN - KPH * cLoB;
    const int iminT = (dTop - NN > 1) ? dTop - NN : 1;
    int lOff = (off_of(dTop) + (tid + 1) - iminT) * 8;
    if (lOff < 0) lOff = 0;
    const bool isL63c = (lane == 63) && (w < 2);
    const bool isL0p  = (lane == 0) && (w > 0);
    const int  ti2 = 2 * (tid + 1);

    float2 wA[KPH], wB[KPH];
    #pragma unroll
    for (int u = 0; u < KPH; ++u) {
        wA[u].x = 0.f; wA[u].y = 0.f; wB[u].x = 0.f; wB[u].y = 0.f;
    }
    const char* WkC = (const char*)Wk;

    auto load16 = [&](float2 (&buf)[KPH], int dtop) {
        #pragma unroll
        for (int u = 0; u < KPH; ++u) {
            const int d = dtop - u;
            buf[u] = *(const float2*)(WkC + lOff);
            const int dec = (d <= NN + 1) ? (d - 2) : (2 * NN + 1 - d);
            lOff -= dec * 8;
            if (lOff < 0) lOff = 0;             // final-chunk tail clamp
        }
    };

    auto chunk = [&](int dhi, float2 (&buf)[KPH]) {
        float sv[KPH + 1], sq[KPH + 1];
        if (w < 2) {
            #pragma unroll
            for (int x = 0; x <= KPH; ++x) {
                sv[x] = rV[w][dhi + 2 - x];
                sq[x] = rD[w][dhi + 2 - x];
            }
        }
        float djf = (float)(dhi - ti2);          // j - i at step u=0
        #pragma unroll
        for (int u = 0; u < KPH; ++u) {
            const int d = dhi - u;
            const float T1 = isL63c ? sv[u + 1] : t1;   // pv @ (i+1, d+1)
            const float T3 = isL63c ? sq[u]     : t3;   // pd @ (i+1, d+2)
            float e = __builtin_fmaf(e1, wh1, T1) + T3;
            const bool ok = bool(((unsigned)(d - 2 - tid) < (unsigned)NN) & rowok);
            e = ok ? e : 0.0f;
            acc = __builtin_fmaf(e * djf, djf, acc);
            djf -= 1.0f;
            const float Wv = buf[u].x, Wh = buf[u].y;
            const float pv = e * Wv;
            const float pd = e * (1.0f - Wv - Wh);
            if (isL0p) { rV[w - 1][d] = pv; rD[w - 1][d] = pd; }
            const float svn = dpp_dn1(pv);
            const float sdn = dpp_dn1(pd);
            t1 = svn;         // pv @ diag d -> term1 at step d-1
            t3 = hPd;         // pd @ diag d+1 -> term3 at step d-1
            hPd = sdn;
            e1 = e; wh1 = Wh;
        }
    };

    for (int t = 0; t < NPHASE; ++t) {
        const int c = t - (2 - w);               // wave 2 leads
        if (c >= cLoB && c <= cHiB) {
            const int dhi = 2 * NN - c * KPH;
            if ((c & 1) == 0) {                  // cLoB ∈ {6,2,0}: all even
                if (c == cLoB) load16(wA, dhi);              // prime
                if (c < cHiB) load16(wB, dhi - KPH);         // prefetch next phase
                chunk(dhi, wA);
            } else {
                if (c < cHiB) load16(wA, dhi - KPH);
                chunk(dhi, wB);
            }
        }
        barrier_lds();
    }

    // block reduce acc -> wlt[k]
    #pragma unroll
    for (int o = 32; o > 0; o >>= 1) acc += __shfl_down(acc, o);
    if (lane == 0) partial[w] = acc;
    barrier_lds();
    if (tid == 0)
        wlt[k] = (partial[0] + partial[1] + partial[2]) * (1.0f / (NN * NN));
}

// final reduction: per-batch means + scalar loss. One wave (64 threads = B).
__global__ __launch_bounds__(64)
void finalize_kernel(const float* __restrict__ sdtw,
                     const float* __restrict__ wlt,
                     float* __restrict__ out)
{
    const int b = threadIdx.x;   // 0..63
    float ls = 0.0f, lt = 0.0f;
    #pragma unroll
    for (int c = 0; c < C_SZ; ++c) {
        ls += sdtw[b * C_SZ + c];
        lt += wlt[b * C_SZ + c];
    }
    ls *= (1.0f / C_SZ);
    lt *= (1.0f / C_SZ);
    out[1 + b]        = ls;
    out[1 + B_SZ + b] = lt;
    float v = 0.5f * ls + 0.5f * lt;
    #pragma unroll
    for (int o = 32; o > 0; o >>= 1) v += __shfl_down(v, o);
    if (b == 0) out[0] = v * (1.0f / B_SZ);
}

extern "C" void kernel_launch(void* const* d_in, const int* in_sizes, int n_in,
                              void* d_out, int out_size, void* d_ws, size_t ws_size,
                              hipStream_t stream) {
    const float* input  = (const float*)d_in[0];
    const float* target = (const float*)d_in[1];
    float* out = (float*)d_out;   // 129 floats

    const size_t cells = (size_t)BC_TOT * NN * NN;
    float2* Wg   = (float2*)d_ws;                       // 105 MB (fits, proven r3-r7)
    float*  sdtw = (float*)((char*)d_ws + cells * sizeof(float2));
    float*  wlt  = sdtw + BC_TOT;

    dtw_fb_kernel<<<BC_TOT, 192, 0, stream>>>(input, target, Wg, sdtw, wlt);
    finalize_kernel<<<1, 64, 0, stream>>>(sdtw, wlt, out);
}